// Round 7
// baseline (72.654 us; speedup 1.0000x reference)
//
#include <hip/hip_runtime.h>
#include <hip/hip_bf16.h>

#define A_N 8192
#define LOG2E 1.44269504f

typedef __attribute__((ext_vector_type(8))) short short8v;
typedef __attribute__((ext_vector_type(4))) float f32x4;
typedef __attribute__((ext_vector_type(4))) int   i32x4;

__device__ inline short f2bf(float x) {
  unsigned u = __builtin_bit_cast(unsigned, x);
  unsigned r = (u + 0x7FFFu + ((u >> 16) & 1u)) >> 16;
  return (short)r;
}
// Compiler-visible exp2 (hazard-handled), replacing raw inline asm.
__device__ inline float fexp2(float x) {
#if __has_builtin(__builtin_amdgcn_exp2f)
  return __builtin_amdgcn_exp2f(x);
#else
  return exp2f(x);
#endif
}
// Compiler-visible bf16 pair pack, replacing raw v_cvt_pk_bf16_f32 asm.
__device__ inline unsigned packbf(float lo, float hi) {
  return (unsigned)(unsigned short)f2bf(lo) | ((unsigned)(unsigned short)f2bf(hi) << 16);
}

// ---------------- K1: fused conv_pool (blocks 0..191) + qkv (blocks 192..223) -----
// R6-verbatim (known good).
__global__ __launch_bounds__(256) void fused_pre(
    const float* __restrict__ x, const float* __restrict__ cw,
    const float* __restrict__ cb, float* __restrict__ sf,
    const int* __restrict__ act, const float* __restrict__ feat,
    const float* __restrict__ wq, const float* __restrict__ bq,
    const float* __restrict__ wk, const float* __restrict__ bk,
    const float* __restrict__ wv, const float* __restrict__ bv,
    const float* __restrict__ wo,
    short* __restrict__ Qo, short* __restrict__ Ko, short* __restrict__ V2T) {
  __shared__ float swq[256], swk[256], swv[256], swo[256];
  __shared__ float sbq[16], sbk[16], sbv[16];
  __shared__ float red[4];
  int tid = threadIdx.x;
  if (blockIdx.x < 192) {
    int bid = blockIdx.x;
    int b  = bid & 1;
    int a  = (bid >> 1) & 1;
    int ch = (bid >> 2) & 15;
    int m  = bid >> 6;
    float w00 = cw[ch*4+0], w01 = cw[ch*4+1], w10 = cw[ch*4+2], w11 = cw[ch*4+3];
    float bias = cb[ch];
    const float* xm = x + (size_t)m * 255 * 255;
    float sum = 0.f;
    for (int p = tid; p < 16384; p += 256) {
      int i = a*128 + (p >> 7);
      int j = b*128 + (p & 127);
      float x00 = (i >= 1 && j >= 1)   ? xm[(i-1)*255 + (j-1)] : 0.f;
      float x01 = (i >= 1 && j <= 254) ? xm[(i-1)*255 + j]     : 0.f;
      float x10 = (i <= 254 && j >= 1) ? xm[i*255 + (j-1)]     : 0.f;
      float x11 = (i <= 254 && j <= 254) ? xm[i*255 + j]       : 0.f;
      float v = fmaf(x00,w00, fmaf(x01,w01, fmaf(x10,w10, fmaf(x11,w11, bias))));
      sum += fmaxf(v, 0.f);
    }
    for (int o = 32; o; o >>= 1) sum += __shfl_down(sum, o, 64);
    int wid = tid >> 6, lane = tid & 63;
    if (lane == 0) red[wid] = sum;
    __syncthreads();
    if (tid == 0) sf[bid] = (red[0]+red[1]+red[2]+red[3]) * (1.0f/16384.0f);
  } else {
    swq[tid] = wq[tid]; swk[tid] = wk[tid]; swv[tid] = wv[tid]; swo[tid] = wo[tid];
    if (tid < 16) { sbq[tid] = bq[tid]; sbk[tid] = bk[tid]; sbv[tid] = bv[tid]; }
    __syncthreads();
    int row = (blockIdx.x - 192) * 256 + tid;
    int idx = act[row];
    const float4* f4 = (const float4*)(feat + (size_t)idx * 16);
    float4 a0 = f4[0], a1 = f4[1], a2 = f4[2], a3 = f4[3];
    float af[16] = {a0.x,a0.y,a0.z,a0.w, a1.x,a1.y,a1.z,a1.w,
                    a2.x,a2.y,a2.z,a2.w, a3.x,a3.y,a3.z,a3.w};
    float q[16], k[16], v[16];
    #pragma unroll
    for (int kk = 0; kk < 16; ++kk) {
      float aq = sbq[kk], ak = sbk[kk], av = sbv[kk];
      #pragma unroll
      for (int f = 0; f < 16; ++f) {
        aq = fmaf(af[f], swq[f*16+kk], aq);
        ak = fmaf(af[f], swk[f*16+kk], ak);
        av = fmaf(af[f], swv[f*16+kk], av);
      }
      q[kk] = aq; k[kk] = ak; v[kk] = av;
    }
    const float qs = 0.25f * LOG2E;
    #pragma unroll
    for (int kk = 0; kk < 16; ++kk) {
      float a = 0.f;
      #pragma unroll
      for (int f = 0; f < 16; ++f) a = fmaf(v[f], swo[f*16+kk], a);
      V2T[(size_t)kk * A_N + row] = f2bf(a);
      Qo[(size_t)row*16 + kk] = f2bf(q[kk] * qs);
      Ko[(size_t)row*16 + kk] = f2bf(k[kk]);
    }
  }
}

// ---------------- K2: cvec (R2-verbatim) ------------------------------------------
__global__ void cvec_kernel(const float* __restrict__ sf, const float* __restrict__ w1,
                            const float* __restrict__ b1, const float* __restrict__ bo,
                            float* __restrict__ cvec) {
  int k = threadIdx.x;
  if (k >= 16) return;
  float c = b1[k];
  for (int s = 0; s < 192; ++s) c = fmaf(sf[s], w1[s*16+k], c);
  for (int f = 0; f < 16; ++f)  c = fmaf(bo[f], w1[(192+f)*16+k], c);
  cvec[k] = c;
}

// ---------------- K3: MFMA flash attention + fused MLP scoring --------------------
// R5's 8-wave structure (1024 j/wave, 32 steps), with inline-asm exp/cvtpk replaced
// by compiler-visible equivalents (hazard-recognizer test).
__global__ __launch_bounds__(512) void attn_score(
    const short* __restrict__ Qb, const short* __restrict__ Kb,
    const short* __restrict__ V2T, const float* __restrict__ cvec,
    const float* __restrict__ w1, const float* __restrict__ w2,
    float* __restrict__ scores) {
  __shared__ float sacc[8][16][16];
  __shared__ float sl[8][16];
  __shared__ float sw1[256];
  __shared__ float scv[16], sw2s[16];
  int tid = threadIdx.x;
  if (tid < 256) sw1[tid] = w1[192*16 + tid];
  if (tid < 16) { scv[tid] = cvec[tid]; sw2s[tid] = w2[tid]; }
  int w = tid >> 6, lane = tid & 63;
  int g = lane >> 4, fi = lane & 15;
  int i0 = blockIdx.x * 16;

  short8v z8 = {};
  short8v qf = z8;
  if (g < 2) qf = *(const short8v*)(Qb + (size_t)(i0 + fi)*16 + g*8);
  const short* kp = Kb + (size_t)(w*1024 + fi)*16 + g*8;
  const short* vp = V2T + (size_t)fi*A_N + w*1024 + g*4;

  f32x4 acc = {0.f,0.f,0.f,0.f};
  float lsum = 0.f;
  #pragma unroll 2
  for (int step = 0; step < 32; ++step) {
    short8v kf0 = z8, kf1 = z8;
    if (g < 2) {
      kf0 = *(const short8v*)(kp);
      kf1 = *(const short8v*)(kp + 256);   // +16 rows
    }
    f32x4 zero4 = {0.f,0.f,0.f,0.f};
    f32x4 e0 = __builtin_amdgcn_mfma_f32_16x16x32_bf16(kf0, qf, zero4, 0, 0, 0);
    f32x4 e1 = __builtin_amdgcn_mfma_f32_16x16x32_bf16(kf1, qf, zero4, 0, 0, 0);
    float p00 = fexp2(e0[0]), p01 = fexp2(e0[1]), p02 = fexp2(e0[2]), p03 = fexp2(e0[3]);
    float p10 = fexp2(e1[0]), p11 = fexp2(e1[1]), p12 = fexp2(e1[2]), p13 = fexp2(e1[3]);
    lsum += ((p00+p01)+(p02+p03)) + ((p10+p11)+(p12+p13));
    i32x4 pk;
    pk[0] = (int)packbf(p00, p01); pk[1] = (int)packbf(p02, p03);
    pk[2] = (int)packbf(p10, p11); pk[3] = (int)packbf(p12, p13);
    short8v pa = __builtin_bit_cast(short8v, pk);
    int2 va = *(const int2*)(vp);
    int2 vb = *(const int2*)(vp + 16);   // +16 j
    i32x4 vv; vv[0] = va.x; vv[1] = va.y; vv[2] = vb.x; vv[3] = vb.y;
    short8v vf = __builtin_bit_cast(short8v, vv);
    acc = __builtin_amdgcn_mfma_f32_16x16x32_bf16(pa, vf, acc, 0, 0, 0);
    kp += 512;  // 32 rows * 16
    vp += 32;   // 32 j
  }
  lsum += __shfl_xor(lsum, 16, 64);
  lsum += __shfl_xor(lsum, 32, 64);
  #pragma unroll
  for (int r = 0; r < 4; ++r) sacc[w][4*g + r][fi] = acc[r];
  if (g == 0) sl[w][fi] = lsum;
  __syncthreads();
  if (tid < 256) {
    int i = tid >> 4, f = tid & 15;
    float o = 0.f, li = 0.f;
    #pragma unroll
    for (int wv = 0; wv < 8; ++wv) { o += sacc[wv][i][f]; li += sl[wv][i]; }
    sacc[0][i][f] = o / li;
  }
  __syncthreads();
  if (tid < 256) {
    int i = tid >> 4, k = tid & 15;
    float h = scv[k];
    #pragma unroll
    for (int f = 0; f < 16; ++f) h = fmaf(sacc[0][i][f], sw1[f*16+k], h);
    h = fmaxf(h, 0.f);
    float t = h * sw2s[k];
    t += __shfl_xor(t, 1, 64);
    t += __shfl_xor(t, 2, 64);
    t += __shfl_xor(t, 4, 64);
    t += __shfl_xor(t, 8, 64);
    if (k == 0) scores[i0 + i] = t;
  }
}

// ---------------- K4: softmax over the 8192 scores (R2-verbatim) ------------------
__global__ __launch_bounds__(1024) void softmax_final(
    const float* __restrict__ scores, float* __restrict__ out) {
  __shared__ float red[16];
  __shared__ float sbc[2];
  int tid = threadIdx.x;
  int lane = tid & 63, wid = tid >> 6;
  float m = -3.4e38f;
  for (int i = tid; i < A_N; i += 1024) m = fmaxf(m, scores[i]);
  for (int o = 32; o; o >>= 1) m = fmaxf(m, __shfl_down(m, o, 64));
  if (lane == 0) red[wid] = m;
  __syncthreads();
  if (tid == 0) {
    float mm = red[0];
    for (int w = 1; w < 16; ++w) mm = fmaxf(mm, red[w]);
    sbc[0] = mm;
  }
  __syncthreads();
  float mx = sbc[0];
  float s = 0.f;
  for (int i = tid; i < A_N; i += 1024) s += __expf(scores[i] - mx);
  for (int o = 32; o; o >>= 1) s += __shfl_down(s, o, 64);
  if (lane == 0) red[wid] = s;
  __syncthreads();
  if (tid == 0) {
    float ss = 0.f;
    for (int w = 0; w < 16; ++w) ss += red[w];
    sbc[1] = ss;
  }
  __syncthreads();
  float inv = 1.0f / sbc[1];
  for (int i = tid; i < A_N; i += 1024) out[i] = __expf(scores[i] - mx) * inv;
}

extern "C" void kernel_launch(void* const* d_in, const int* in_sizes, int n_in,
                              void* d_out, int out_size, void* d_ws, size_t ws_size,
                              hipStream_t stream) {
  const float* x      = (const float*)d_in[0];
  const int*   act    = (const int*)  d_in[1];
  const float* feat   = (const float*)d_in[2];
  const float* conv_w = (const float*)d_in[3];
  const float* conv_b = (const float*)d_in[4];
  const float* wq     = (const float*)d_in[5];
  const float* bq     = (const float*)d_in[6];
  const float* wk     = (const float*)d_in[7];
  const float* bk     = (const float*)d_in[8];
  const float* wv     = (const float*)d_in[9];
  const float* bv     = (const float*)d_in[10];
  const float* wo     = (const float*)d_in[11];
  const float* bo     = (const float*)d_in[12];
  const float* w1     = (const float*)d_in[13];
  const float* b1     = (const float*)d_in[14];
  const float* w2     = (const float*)d_in[15];
  // d_in[16] = mlp_b2: softmax shift-invariant, dropped.

  char* wsb = (char*)d_ws;
  float* sf     = (float*)(wsb);             // 192 floats
  float* cvec   = (float*)(wsb + 1024);      // 16
  float* scores = (float*)(wsb + 2048);      // 8192
  short* Qb     = (short*)(wsb + 65536);             // 8192*16 bf16
  short* Kb     = (short*)(wsb + 65536 + 262144);    // 8192*16 bf16
  short* V2T    = (short*)(wsb + 65536 + 524288);    // 16*8192 bf16
  float* out    = (float*)d_out;

  fused_pre    <<<224, 256, 0, stream>>>(x, conv_w, conv_b, sf,
                                         act, feat, wq, bq, wk, bk, wv, bv, wo,
                                         Qb, Kb, V2T);
  cvec_kernel  <<<1, 64, 0, stream>>>(sf, w1, b1, bo, cvec);
  attn_score   <<<A_N/16, 512, 0, stream>>>(Qb, Kb, V2T, cvec, w1, w2, scores);
  softmax_final<<<1, 1024, 0, stream>>>(scores, out);
}

// Round 9
// 50.380 us; speedup vs baseline: 1.4421x; 1.4421x over previous
//
#include <hip/hip_runtime.h>
#include <hip/hip_bf16.h>

#define A_N 8192
#define LOG2E 1.44269504f

typedef __attribute__((ext_vector_type(8))) short short8v;
typedef __attribute__((ext_vector_type(4))) float f32x4;
typedef __attribute__((ext_vector_type(4))) int   i32x4;

__device__ inline short f2bf(float x) {
  unsigned u = __builtin_bit_cast(unsigned, x);
  unsigned r = (u + 0x7FFFu + ((u >> 16) & 1u)) >> 16;
  return (short)r;
}
// Compiler-visible exp2 (hazard-handled) — proven safe in R7.
__device__ inline float fexp2(float x) {
#if __has_builtin(__builtin_amdgcn_exp2f)
  return __builtin_amdgcn_exp2f(x);
#else
  return exp2f(x);
#endif
}
// Compiler-visible bf16 pair pack (RNE), proven safe in R7.
__device__ inline unsigned packbf(float lo, float hi) {
  return (unsigned)(unsigned short)f2bf(lo) | ((unsigned)(unsigned short)f2bf(hi) << 16);
}

// ---------------- K1: fused conv_pool (blocks 0..191) + qkv (blocks 192..223) -----
// conv/qkv math R7-verbatim; ONLY the V2 store layout changed (pre-swizzled V2S).
__global__ __launch_bounds__(256) void fused_pre(
    const float* __restrict__ x, const float* __restrict__ cw,
    const float* __restrict__ cb, float* __restrict__ sf,
    const int* __restrict__ act, const float* __restrict__ feat,
    const float* __restrict__ wq, const float* __restrict__ bq,
    const float* __restrict__ wk, const float* __restrict__ bk,
    const float* __restrict__ wv, const float* __restrict__ bv,
    const float* __restrict__ wo,
    short* __restrict__ Qo, short* __restrict__ Ko, short* __restrict__ V2S) {
  __shared__ float swq[256], swk[256], swv[256], swo[256];
  __shared__ float sbq[16], sbk[16], sbv[16];
  __shared__ float red[4];
  int tid = threadIdx.x;
  if (blockIdx.x < 192) {
    int bid = blockIdx.x;
    int b  = bid & 1;
    int a  = (bid >> 1) & 1;
    int ch = (bid >> 2) & 15;
    int m  = bid >> 6;
    float w00 = cw[ch*4+0], w01 = cw[ch*4+1], w10 = cw[ch*4+2], w11 = cw[ch*4+3];
    float bias = cb[ch];
    const float* xm = x + (size_t)m * 255 * 255;
    float sum = 0.f;
    for (int p = tid; p < 16384; p += 256) {
      int i = a*128 + (p >> 7);
      int j = b*128 + (p & 127);
      float x00 = (i >= 1 && j >= 1)   ? xm[(i-1)*255 + (j-1)] : 0.f;
      float x01 = (i >= 1 && j <= 254) ? xm[(i-1)*255 + j]     : 0.f;
      float x10 = (i <= 254 && j >= 1) ? xm[i*255 + (j-1)]     : 0.f;
      float x11 = (i <= 254 && j <= 254) ? xm[i*255 + j]       : 0.f;
      float v = fmaf(x00,w00, fmaf(x01,w01, fmaf(x10,w10, fmaf(x11,w11, bias))));
      sum += fmaxf(v, 0.f);
    }
    for (int o = 32; o; o >>= 1) sum += __shfl_down(sum, o, 64);
    int wid = tid >> 6, lane = tid & 63;
    if (lane == 0) red[wid] = sum;
    __syncthreads();
    if (tid == 0) sf[bid] = (red[0]+red[1]+red[2]+red[3]) * (1.0f/16384.0f);
  } else {
    swq[tid] = wq[tid]; swk[tid] = wk[tid]; swv[tid] = wv[tid]; swo[tid] = wo[tid];
    if (tid < 16) { sbq[tid] = bq[tid]; sbk[tid] = bk[tid]; sbv[tid] = bv[tid]; }
    __syncthreads();
    int row = (blockIdx.x - 192) * 256 + tid;
    int idx = act[row];
    const float4* f4 = (const float4*)(feat + (size_t)idx * 16);
    float4 a0 = f4[0], a1 = f4[1], a2 = f4[2], a3 = f4[3];
    float af[16] = {a0.x,a0.y,a0.z,a0.w, a1.x,a1.y,a1.z,a1.w,
                    a2.x,a2.y,a2.z,a2.w, a3.x,a3.y,a3.z,a3.w};
    float q[16], k[16], v[16];
    #pragma unroll
    for (int kk = 0; kk < 16; ++kk) {
      float aq = sbq[kk], ak = sbk[kk], av = sbv[kk];
      #pragma unroll
      for (int f = 0; f < 16; ++f) {
        aq = fmaf(af[f], swq[f*16+kk], aq);
        ak = fmaf(af[f], swk[f*16+kk], ak);
        av = fmaf(af[f], swv[f*16+kk], av);
      }
      q[kk] = aq; k[kk] = ak; v[kk] = av;
    }
    const float qs = 0.25f * LOG2E;
    // swizzle indices for this row (j = row): V2S[(s*64 + g*16 + f)*8 + hi*4 + r]
    int s  = row >> 5;
    int jj = row & 31;
    int hi = jj >> 4;
    int m2 = jj & 15;
    int gsw = m2 >> 2;
    int rsw = m2 & 3;
    size_t vbase = (size_t)s * 512 + (size_t)gsw * 128 + hi * 4 + rsw;
    #pragma unroll
    for (int kk = 0; kk < 16; ++kk) {
      float a = 0.f;
      #pragma unroll
      for (int f = 0; f < 16; ++f) a = fmaf(v[f], swo[f*16+kk], a);
      V2S[vbase + (size_t)kk * 8] = f2bf(a);
      Qo[(size_t)row*16 + kk] = f2bf(q[kk] * qs);
      Ko[(size_t)row*16 + kk] = f2bf(k[kk]);
    }
  }
}

// ---------------- K2: cvec (R2-verbatim) ------------------------------------------
__global__ void cvec_kernel(const float* __restrict__ sf, const float* __restrict__ w1,
                            const float* __restrict__ b1, const float* __restrict__ bo,
                            float* __restrict__ cvec) {
  int k = threadIdx.x;
  if (k >= 16) return;
  float c = b1[k];
  for (int s = 0; s < 192; ++s) c = fmaf(sf[s], w1[s*16+k], c);
  for (int f = 0; f < 16; ++f)  c = fmaf(bo[f], w1[(192+f)*16+k], c);
  cvec[k] = c;
}

// ---------------- K3: MFMA flash attention + fused MLP scoring --------------------
// Block = 32 i-rows (2 Q frags), 16 waves = 16-way j-split (512 j each, 16 steps of
// 32 j). K loads shared by both frags; V via pre-swizzled V2S (1 contiguous dwordx4
// per step). All ops are builtins (hazard-safe, per R7's finding).
__global__ __launch_bounds__(1024) void attn_score(
    const short* __restrict__ Qb, const short* __restrict__ Kb,
    const short* __restrict__ V2S, const float* __restrict__ cvec,
    const float* __restrict__ w1, const float* __restrict__ w2,
    float* __restrict__ scores) {
  __shared__ float sacc[16][32][16];
  __shared__ float sl[16][32];
  __shared__ float sw1[256];
  __shared__ float scv[16], sw2s[16];
  int tid = threadIdx.x;
  if (tid < 256) sw1[tid] = w1[192*16 + tid];
  if (tid < 16) { scv[tid] = cvec[tid]; sw2s[tid] = w2[tid]; }
  int w = tid >> 6, lane = tid & 63;
  int g = lane >> 4, fi = lane & 15;
  int i0 = blockIdx.x * 32;

  short8v z8 = {};
  short8v qfa = z8, qfb = z8;
  if (g < 2) {
    qfa = *(const short8v*)(Qb + (size_t)(i0 + fi)*16 + g*8);
    qfb = *(const short8v*)(Qb + (size_t)(i0 + 16 + fi)*16 + g*8);
  }
  const short* kp = Kb + (size_t)(w*512 + fi)*16 + g*8;
  const short* vp = V2S + (size_t)(w*1024 + lane)*8;

  f32x4 acca = {0.f,0.f,0.f,0.f}, accb = {0.f,0.f,0.f,0.f};
  float lsa = 0.f, lsb = 0.f;
  #pragma unroll 2
  for (int step = 0; step < 16; ++step) {
    short8v kf0 = z8, kf1 = z8;
    if (g < 2) {
      kf0 = *(const short8v*)(kp);
      kf1 = *(const short8v*)(kp + 256);   // +16 rows
    }
    i32x4 vv = *(const i32x4*)(vp);
    short8v vf = __builtin_bit_cast(short8v, vv);
    f32x4 zero4 = {0.f,0.f,0.f,0.f};
    f32x4 e0a = __builtin_amdgcn_mfma_f32_16x16x32_bf16(kf0, qfa, zero4, 0, 0, 0);
    f32x4 e1a = __builtin_amdgcn_mfma_f32_16x16x32_bf16(kf1, qfa, zero4, 0, 0, 0);
    f32x4 e0b = __builtin_amdgcn_mfma_f32_16x16x32_bf16(kf0, qfb, zero4, 0, 0, 0);
    f32x4 e1b = __builtin_amdgcn_mfma_f32_16x16x32_bf16(kf1, qfb, zero4, 0, 0, 0);
    {
      float p0 = fexp2(e0a[0]), p1 = fexp2(e0a[1]), p2 = fexp2(e0a[2]), p3 = fexp2(e0a[3]);
      float p4 = fexp2(e1a[0]), p5 = fexp2(e1a[1]), p6 = fexp2(e1a[2]), p7 = fexp2(e1a[3]);
      lsa += ((p0+p1)+(p2+p3)) + ((p4+p5)+(p6+p7));
      i32x4 pk;
      pk[0] = (int)packbf(p0, p1); pk[1] = (int)packbf(p2, p3);
      pk[2] = (int)packbf(p4, p5); pk[3] = (int)packbf(p6, p7);
      acca = __builtin_amdgcn_mfma_f32_16x16x32_bf16(__builtin_bit_cast(short8v, pk), vf, acca, 0, 0, 0);
    }
    {
      float p0 = fexp2(e0b[0]), p1 = fexp2(e0b[1]), p2 = fexp2(e0b[2]), p3 = fexp2(e0b[3]);
      float p4 = fexp2(e1b[0]), p5 = fexp2(e1b[1]), p6 = fexp2(e1b[2]), p7 = fexp2(e1b[3]);
      lsb += ((p0+p1)+(p2+p3)) + ((p4+p5)+(p6+p7));
      i32x4 pk;
      pk[0] = (int)packbf(p0, p1); pk[1] = (int)packbf(p2, p3);
      pk[2] = (int)packbf(p4, p5); pk[3] = (int)packbf(p6, p7);
      accb = __builtin_amdgcn_mfma_f32_16x16x32_bf16(__builtin_bit_cast(short8v, pk), vf, accb, 0, 0, 0);
    }
    kp += 512;  // 32 rows * 16
    vp += 512;  // 64 lanes * 8 shorts
  }
  lsa += __shfl_xor(lsa, 16, 64); lsa += __shfl_xor(lsa, 32, 64);
  lsb += __shfl_xor(lsb, 16, 64); lsb += __shfl_xor(lsb, 32, 64);
  #pragma unroll
  for (int r = 0; r < 4; ++r) {
    sacc[w][4*g + r][fi]      = acca[r];
    sacc[w][16 + 4*g + r][fi] = accb[r];
  }
  if (g == 0) { sl[w][fi] = lsa; sl[w][16 + fi] = lsb; }
  __syncthreads();
  if (tid < 512) {
    int i = tid >> 4, f = tid & 15;
    float o = 0.f, li = 0.f;
    #pragma unroll
    for (int wv = 0; wv < 16; ++wv) { o += sacc[wv][i][f]; li += sl[wv][i]; }
    sacc[0][i][f] = o / li;
  }
  __syncthreads();
  if (tid < 512) {
    int i = tid >> 4, k = tid & 15;
    float h = scv[k];
    #pragma unroll
    for (int f = 0; f < 16; ++f) h = fmaf(sacc[0][i][f], sw1[f*16+k], h);
    h = fmaxf(h, 0.f);
    float t = h * sw2s[k];
    t += __shfl_xor(t, 1, 64);
    t += __shfl_xor(t, 2, 64);
    t += __shfl_xor(t, 4, 64);
    t += __shfl_xor(t, 8, 64);
    if (k == 0) scores[i0 + i] = t;
  }
}

// ---------------- K4: softmax over the 8192 scores (R2-verbatim) ------------------
__global__ __launch_bounds__(1024) void softmax_final(
    const float* __restrict__ scores, float* __restrict__ out) {
  __shared__ float red[16];
  __shared__ float sbc[2];
  int tid = threadIdx.x;
  int lane = tid & 63, wid = tid >> 6;
  float m = -3.4e38f;
  for (int i = tid; i < A_N; i += 1024) m = fmaxf(m, scores[i]);
  for (int o = 32; o; o >>= 1) m = fmaxf(m, __shfl_down(m, o, 64));
  if (lane == 0) red[wid] = m;
  __syncthreads();
  if (tid == 0) {
    float mm = red[0];
    for (int w = 1; w < 16; ++w) mm = fmaxf(mm, red[w]);
    sbc[0] = mm;
  }
  __syncthreads();
  float mx = sbc[0];
  float s = 0.f;
  for (int i = tid; i < A_N; i += 1024) s += __expf(scores[i] - mx);
  for (int o = 32; o; o >>= 1) s += __shfl_down(s, o, 64);
  if (lane == 0) red[wid] = s;
  __syncthreads();
  if (tid == 0) {
    float ss = 0.f;
    for (int w = 0; w < 16; ++w) ss += red[w];
    sbc[1] = ss;
  }
  __syncthreads();
  float inv = 1.0f / sbc[1];
  for (int i = tid; i < A_N; i += 1024) out[i] = __expf(scores[i] - mx) * inv;
}

extern "C" void kernel_launch(void* const* d_in, const int* in_sizes, int n_in,
                              void* d_out, int out_size, void* d_ws, size_t ws_size,
                              hipStream_t stream) {
  const float* x      = (const float*)d_in[0];
  const int*   act    = (const int*)  d_in[1];
  const float* feat   = (const float*)d_in[2];
  const float* conv_w = (const float*)d_in[3];
  const float* conv_b = (const float*)d_in[4];
  const float* wq     = (const float*)d_in[5];
  const float* bq     = (const float*)d_in[6];
  const float* wk     = (const float*)d_in[7];
  const float* bk     = (const float*)d_in[8];
  const float* wv     = (const float*)d_in[9];
  const float* bv     = (const float*)d_in[10];
  const float* wo     = (const float*)d_in[11];
  const float* bo     = (const float*)d_in[12];
  const float* w1     = (const float*)d_in[13];
  const float* b1     = (const float*)d_in[14];
  const float* w2     = (const float*)d_in[15];
  // d_in[16] = mlp_b2: softmax shift-invariant, dropped.

  char* wsb = (char*)d_ws;
  float* sf     = (float*)(wsb);             // 192 floats
  float* cvec   = (float*)(wsb + 1024);      // 16
  float* scores = (float*)(wsb + 2048);      // 8192
  short* Qb     = (short*)(wsb + 65536);             // 8192*16 bf16
  short* Kb     = (short*)(wsb + 65536 + 262144);    // 8192*16 bf16
  short* V2S    = (short*)(wsb + 65536 + 524288);    // 256 steps * 64 lanes * 8 bf16
  float* out    = (float*)d_out;

  fused_pre    <<<224, 256, 0, stream>>>(x, conv_w, conv_b, sf,
                                         act, feat, wq, bq, wk, bk, wv, bv, wo,
                                         Qb, Kb, V2S);
  cvec_kernel  <<<1, 64, 0, stream>>>(sf, w1, b1, bo, cvec);
  attn_score   <<<A_N/32, 1024, 0, stream>>>(Qb, Kb, V2S, cvec, w1, w2, scores);
  softmax_final<<<1, 1024, 0, stream>>>(scores, out);
}

// Round 10
// 46.060 us; speedup vs baseline: 1.5774x; 1.0938x over previous
//
#include <hip/hip_runtime.h>
#include <hip/hip_bf16.h>

#define A_N 8192
#define LOG2E 1.44269504f

typedef __attribute__((ext_vector_type(8))) short short8v;
typedef __attribute__((ext_vector_type(4))) float f32x4;
typedef __attribute__((ext_vector_type(4))) int   i32x4;

__device__ inline short f2bf(float x) {
  unsigned u = __builtin_bit_cast(unsigned, x);
  unsigned r = (u + 0x7FFFu + ((u >> 16) & 1u)) >> 16;
  return (short)r;
}
// Compiler-visible exp2 (hazard-handled) — proven safe in R7.
__device__ inline float fexp2(float x) {
#if __has_builtin(__builtin_amdgcn_exp2f)
  return __builtin_amdgcn_exp2f(x);
#else
  return exp2f(x);
#endif
}
// Compiler-visible bf16 pair pack (RNE), proven safe in R7/R9.
// NOTE: never use raw inline-asm v_cvt_pk feeding MFMA (R3-R5 hazard bug).
__device__ inline unsigned packbf(float lo, float hi) {
  return (unsigned)(unsigned short)f2bf(lo) | ((unsigned)(unsigned short)f2bf(hi) << 16);
}

// ---------------- K1: fused conv_pool (blocks 0..191) + qkv (192..223) ------------
// R9-verbatim bodies; block 0 also zeroes the attn completion counter.
__global__ __launch_bounds__(256) void fused_pre(
    const float* __restrict__ x, const float* __restrict__ cw,
    const float* __restrict__ cb, float* __restrict__ sf,
    const int* __restrict__ act, const float* __restrict__ feat,
    const float* __restrict__ wq, const float* __restrict__ bq,
    const float* __restrict__ wk, const float* __restrict__ bk,
    const float* __restrict__ wv, const float* __restrict__ bv,
    const float* __restrict__ wo,
    short* __restrict__ Qo, short* __restrict__ Ko, short* __restrict__ V2S,
    int* __restrict__ counter) {
  __shared__ float swq[256], swk[256], swv[256], swo[256];
  __shared__ float sbq[16], sbk[16], sbv[16];
  __shared__ float red[4];
  int tid = threadIdx.x;
  if (blockIdx.x == 0 && tid == 0) *counter = 0;
  if (blockIdx.x < 192) {
    int bid = blockIdx.x;
    int b  = bid & 1;
    int a  = (bid >> 1) & 1;
    int ch = (bid >> 2) & 15;
    int m  = bid >> 6;
    float w00 = cw[ch*4+0], w01 = cw[ch*4+1], w10 = cw[ch*4+2], w11 = cw[ch*4+3];
    float bias = cb[ch];
    const float* xm = x + (size_t)m * 255 * 255;
    float sum = 0.f;
    for (int p = tid; p < 16384; p += 256) {
      int i = a*128 + (p >> 7);
      int j = b*128 + (p & 127);
      float x00 = (i >= 1 && j >= 1)   ? xm[(i-1)*255 + (j-1)] : 0.f;
      float x01 = (i >= 1 && j <= 254) ? xm[(i-1)*255 + j]     : 0.f;
      float x10 = (i <= 254 && j >= 1) ? xm[i*255 + (j-1)]     : 0.f;
      float x11 = (i <= 254 && j <= 254) ? xm[i*255 + j]       : 0.f;
      float v = fmaf(x00,w00, fmaf(x01,w01, fmaf(x10,w10, fmaf(x11,w11, bias))));
      sum += fmaxf(v, 0.f);
    }
    for (int o = 32; o; o >>= 1) sum += __shfl_down(sum, o, 64);
    int wid = tid >> 6, lane = tid & 63;
    if (lane == 0) red[wid] = sum;
    __syncthreads();
    if (tid == 0) sf[bid] = (red[0]+red[1]+red[2]+red[3]) * (1.0f/16384.0f);
  } else {
    swq[tid] = wq[tid]; swk[tid] = wk[tid]; swv[tid] = wv[tid]; swo[tid] = wo[tid];
    if (tid < 16) { sbq[tid] = bq[tid]; sbk[tid] = bk[tid]; sbv[tid] = bv[tid]; }
    __syncthreads();
    int row = (blockIdx.x - 192) * 256 + tid;
    int idx = act[row];
    const float4* f4 = (const float4*)(feat + (size_t)idx * 16);
    float4 a0 = f4[0], a1 = f4[1], a2 = f4[2], a3 = f4[3];
    float af[16] = {a0.x,a0.y,a0.z,a0.w, a1.x,a1.y,a1.z,a1.w,
                    a2.x,a2.y,a2.z,a2.w, a3.x,a3.y,a3.z,a3.w};
    float q[16], k[16], v[16];
    #pragma unroll
    for (int kk = 0; kk < 16; ++kk) {
      float aq = sbq[kk], ak = sbk[kk], av = sbv[kk];
      #pragma unroll
      for (int f = 0; f < 16; ++f) {
        aq = fmaf(af[f], swq[f*16+kk], aq);
        ak = fmaf(af[f], swk[f*16+kk], ak);
        av = fmaf(af[f], swv[f*16+kk], av);
      }
      q[kk] = aq; k[kk] = ak; v[kk] = av;
    }
    const float qs = 0.25f * LOG2E;
    int s  = row >> 5;
    int jj = row & 31;
    int hi = jj >> 4;
    int m2 = jj & 15;
    int gsw = m2 >> 2;
    int rsw = m2 & 3;
    size_t vbase = (size_t)s * 512 + (size_t)gsw * 128 + hi * 4 + rsw;
    #pragma unroll
    for (int kk = 0; kk < 16; ++kk) {
      float a = 0.f;
      #pragma unroll
      for (int f = 0; f < 16; ++f) a = fmaf(v[f], swo[f*16+kk], a);
      V2S[vbase + (size_t)kk * 8] = f2bf(a);
      Qo[(size_t)row*16 + kk] = f2bf(q[kk] * qs);
      Ko[(size_t)row*16 + kk] = f2bf(k[kk]);
    }
  }
}

// ---------------- K2: attn + MLP + scores + (last block) final softmax ------------
// R9-verbatim main loop (unroll 4); cvec computed per-block by lanes 0-15 (identical
// math to old cvec_kernel); scores via agent-scope atomics; last-block-done softmax.
__global__ __launch_bounds__(1024) void attn_score(
    const short* __restrict__ Qb, const short* __restrict__ Kb,
    const short* __restrict__ V2S, const float* __restrict__ sf,
    const float* __restrict__ w1, const float* __restrict__ b1,
    const float* __restrict__ bo, const float* __restrict__ w2,
    float* __restrict__ scores, int* __restrict__ counter,
    float* __restrict__ outp) {
  __shared__ float sacc[16][32][16];
  __shared__ float sl[16][32];
  __shared__ float sw1[256];
  __shared__ float scv[16], sw2s[16];
  __shared__ float red2[16];
  __shared__ float sbc2[2];
  __shared__ int slastS;
  int tid = threadIdx.x;
  if (tid < 256) sw1[tid] = w1[192*16 + tid];
  if (tid < 16) {
    float c = b1[tid];
    for (int s = 0; s < 192; ++s) c = fmaf(sf[s], w1[s*16+tid], c);
    for (int f = 0; f < 16; ++f)  c = fmaf(bo[f], w1[(192+f)*16+tid], c);
    scv[tid] = c;
    sw2s[tid] = w2[tid];
  }
  int w = tid >> 6, lane = tid & 63;
  int g = lane >> 4, fi = lane & 15;
  int i0 = blockIdx.x * 32;

  short8v z8 = {};
  short8v qfa = z8, qfb = z8;
  if (g < 2) {
    qfa = *(const short8v*)(Qb + (size_t)(i0 + fi)*16 + g*8);
    qfb = *(const short8v*)(Qb + (size_t)(i0 + 16 + fi)*16 + g*8);
  }
  const short* kp = Kb + (size_t)(w*512 + fi)*16 + g*8;
  const short* vp = V2S + (size_t)(w*1024 + lane)*8;

  f32x4 acca = {0.f,0.f,0.f,0.f}, accb = {0.f,0.f,0.f,0.f};
  float lsa = 0.f, lsb = 0.f;
  #pragma unroll 4
  for (int step = 0; step < 16; ++step) {
    short8v kf0 = z8, kf1 = z8;
    if (g < 2) {
      kf0 = *(const short8v*)(kp);
      kf1 = *(const short8v*)(kp + 256);   // +16 rows
    }
    i32x4 vv = *(const i32x4*)(vp);
    short8v vf = __builtin_bit_cast(short8v, vv);
    f32x4 zero4 = {0.f,0.f,0.f,0.f};
    f32x4 e0a = __builtin_amdgcn_mfma_f32_16x16x32_bf16(kf0, qfa, zero4, 0, 0, 0);
    f32x4 e1a = __builtin_amdgcn_mfma_f32_16x16x32_bf16(kf1, qfa, zero4, 0, 0, 0);
    f32x4 e0b = __builtin_amdgcn_mfma_f32_16x16x32_bf16(kf0, qfb, zero4, 0, 0, 0);
    f32x4 e1b = __builtin_amdgcn_mfma_f32_16x16x32_bf16(kf1, qfb, zero4, 0, 0, 0);
    {
      float p0 = fexp2(e0a[0]), p1 = fexp2(e0a[1]), p2 = fexp2(e0a[2]), p3 = fexp2(e0a[3]);
      float p4 = fexp2(e1a[0]), p5 = fexp2(e1a[1]), p6 = fexp2(e1a[2]), p7 = fexp2(e1a[3]);
      lsa += ((p0+p1)+(p2+p3)) + ((p4+p5)+(p6+p7));
      i32x4 pk;
      pk[0] = (int)packbf(p0, p1); pk[1] = (int)packbf(p2, p3);
      pk[2] = (int)packbf(p4, p5); pk[3] = (int)packbf(p6, p7);
      acca = __builtin_amdgcn_mfma_f32_16x16x32_bf16(__builtin_bit_cast(short8v, pk), vf, acca, 0, 0, 0);
    }
    {
      float p0 = fexp2(e0b[0]), p1 = fexp2(e0b[1]), p2 = fexp2(e0b[2]), p3 = fexp2(e0b[3]);
      float p4 = fexp2(e1b[0]), p5 = fexp2(e1b[1]), p6 = fexp2(e1b[2]), p7 = fexp2(e1b[3]);
      lsb += ((p0+p1)+(p2+p3)) + ((p4+p5)+(p6+p7));
      i32x4 pk;
      pk[0] = (int)packbf(p0, p1); pk[1] = (int)packbf(p2, p3);
      pk[2] = (int)packbf(p4, p5); pk[3] = (int)packbf(p6, p7);
      accb = __builtin_amdgcn_mfma_f32_16x16x32_bf16(__builtin_bit_cast(short8v, pk), vf, accb, 0, 0, 0);
    }
    kp += 512;  // 32 rows * 16
    vp += 512;  // 64 lanes * 8 shorts
  }
  lsa += __shfl_xor(lsa, 16, 64); lsa += __shfl_xor(lsa, 32, 64);
  lsb += __shfl_xor(lsb, 16, 64); lsb += __shfl_xor(lsb, 32, 64);
  #pragma unroll
  for (int r = 0; r < 4; ++r) {
    sacc[w][4*g + r][fi]      = acca[r];
    sacc[w][16 + 4*g + r][fi] = accb[r];
  }
  if (g == 0) { sl[w][fi] = lsa; sl[w][16 + fi] = lsb; }
  __syncthreads();
  if (tid < 512) {
    int i = tid >> 4, f = tid & 15;
    float o = 0.f, li = 0.f;
    #pragma unroll
    for (int wv = 0; wv < 16; ++wv) { o += sacc[wv][i][f]; li += sl[wv][i]; }
    sacc[0][i][f] = o / li;
  }
  __syncthreads();
  if (tid < 512) {
    int i = tid >> 4, k = tid & 15;
    float h = scv[k];
    #pragma unroll
    for (int f = 0; f < 16; ++f) h = fmaf(sacc[0][i][f], sw1[f*16+k], h);
    h = fmaxf(h, 0.f);
    float t = h * sw2s[k];
    t += __shfl_xor(t, 1, 64);
    t += __shfl_xor(t, 2, 64);
    t += __shfl_xor(t, 4, 64);
    t += __shfl_xor(t, 8, 64);
    if (k == 0)
      __hip_atomic_store(&scores[i0 + i], t, __ATOMIC_RELAXED, __HIP_MEMORY_SCOPE_AGENT);
  }
  __syncthreads();
  if (tid == 0)
    slastS = __hip_atomic_fetch_add(counter, 1, __ATOMIC_ACQ_REL, __HIP_MEMORY_SCOPE_AGENT);
  __syncthreads();
  if (slastS != (A_N/32) - 1) return;

  // ---- last block: final softmax over 8192 scores (register-cached) ----
  float sv[8];
  #pragma unroll
  for (int u = 0; u < 8; ++u)
    sv[u] = __hip_atomic_load(&scores[tid + u*1024], __ATOMIC_RELAXED, __HIP_MEMORY_SCOPE_AGENT);
  int lane2 = tid & 63, wid2 = tid >> 6;
  float m = -3.4e38f;
  #pragma unroll
  for (int u = 0; u < 8; ++u) m = fmaxf(m, sv[u]);
  for (int o = 32; o; o >>= 1) m = fmaxf(m, __shfl_down(m, o, 64));
  if (lane2 == 0) red2[wid2] = m;
  __syncthreads();
  if (tid == 0) {
    float mm = red2[0];
    for (int wv = 1; wv < 16; ++wv) mm = fmaxf(mm, red2[wv]);
    sbc2[0] = mm;
  }
  __syncthreads();
  float mx = sbc2[0];
  float s = 0.f;
  #pragma unroll
  for (int u = 0; u < 8; ++u) s += __expf(sv[u] - mx);
  for (int o = 32; o; o >>= 1) s += __shfl_down(s, o, 64);
  if (lane2 == 0) red2[wid2] = s;
  __syncthreads();
  if (tid == 0) {
    float ss = 0.f;
    for (int wv = 0; wv < 16; ++wv) ss += red2[wv];
    sbc2[1] = ss;
  }
  __syncthreads();
  float inv = 1.0f / sbc2[1];
  #pragma unroll
  for (int u = 0; u < 8; ++u)
    outp[tid + u*1024] = __expf(sv[u] - mx) * inv;
}

extern "C" void kernel_launch(void* const* d_in, const int* in_sizes, int n_in,
                              void* d_out, int out_size, void* d_ws, size_t ws_size,
                              hipStream_t stream) {
  const float* x      = (const float*)d_in[0];
  const int*   act    = (const int*)  d_in[1];
  const float* feat   = (const float*)d_in[2];
  const float* conv_w = (const float*)d_in[3];
  const float* conv_b = (const float*)d_in[4];
  const float* wq     = (const float*)d_in[5];
  const float* bq     = (const float*)d_in[6];
  const float* wk     = (const float*)d_in[7];
  const float* bk     = (const float*)d_in[8];
  const float* wv     = (const float*)d_in[9];
  const float* bv     = (const float*)d_in[10];
  const float* wo     = (const float*)d_in[11];
  const float* bo     = (const float*)d_in[12];
  const float* w1     = (const float*)d_in[13];
  const float* b1     = (const float*)d_in[14];
  const float* w2     = (const float*)d_in[15];
  // d_in[16] = mlp_b2: softmax shift-invariant, dropped.

  char* wsb = (char*)d_ws;
  float* sf     = (float*)(wsb);             // 192 floats
  int*   ctr    = (int*)  (wsb + 1536);      // completion counter
  float* scores = (float*)(wsb + 2048);      // 8192 floats
  short* Qb     = (short*)(wsb + 65536);             // 8192*16 bf16
  short* Kb     = (short*)(wsb + 65536 + 262144);    // 8192*16 bf16
  short* V2S    = (short*)(wsb + 65536 + 524288);    // 8192*16 bf16 (swizzled)
  float* out    = (float*)d_out;

  fused_pre  <<<224, 256, 0, stream>>>(x, conv_w, conv_b, sf,
                                       act, feat, wq, bq, wk, bk, wv, bv, wo,
                                       Qb, Kb, V2S, ctr);
  attn_score <<<A_N/32, 1024, 0, stream>>>(Qb, Kb, V2S, sf, w1, b1, bo, w2,
                                           scores, ctr, out);
}

// Round 11
// 41.598 us; speedup vs baseline: 1.7466x; 1.1073x over previous
//
#include <hip/hip_runtime.h>
#include <hip/hip_bf16.h>

#define A_N 8192
#define LOG2E 1.44269504f

typedef __attribute__((ext_vector_type(8))) short short8v;
typedef __attribute__((ext_vector_type(4))) float f32x4;
typedef __attribute__((ext_vector_type(4))) int   i32x4;

__device__ inline short f2bf(float x) {
  unsigned u = __builtin_bit_cast(unsigned, x);
  unsigned r = (u + 0x7FFFu + ((u >> 16) & 1u)) >> 16;
  return (short)r;
}
// Compiler-visible exp2 (hazard-handled) — proven safe in R7.
__device__ inline float fexp2(float x) {
#if __has_builtin(__builtin_amdgcn_exp2f)
  return __builtin_amdgcn_exp2f(x);
#else
  return exp2f(x);
#endif
}
// Packed bf16 convert (RNE, bit-identical to manual round-and-pack) via the
// HIP intrinsic -> lowers to v_cvt_pk_bf16_f32, compiler-scheduled (hazard-safe).
// NOTE: never raw inline-asm v_cvt_pk feeding MFMA (R3-R5 hazard bug).
__device__ inline unsigned cvtpk2(float lo, float hi) {
  float2 t; t.x = lo; t.y = hi;
  __hip_bfloat162 h = __float22bfloat162_rn(t);
  unsigned r; __builtin_memcpy(&r, &h, 4);
  return r;
}

// ---------------- K1: fused conv partials (blocks 0..1535) + qkv (1536..1567) -----
// Conv split 8-way per (m,ch,quadrant) for latency hiding; partial sums to sfp.
// qkv body R10-verbatim. Block 0 zeroes the attn completion counter.
__global__ __launch_bounds__(256) void fused_pre(
    const float* __restrict__ x, const float* __restrict__ cw,
    const float* __restrict__ cb, float* __restrict__ sfp,
    const int* __restrict__ act, const float* __restrict__ feat,
    const float* __restrict__ wq, const float* __restrict__ bq,
    const float* __restrict__ wk, const float* __restrict__ bk,
    const float* __restrict__ wv, const float* __restrict__ bv,
    const float* __restrict__ wo,
    short* __restrict__ Qo, short* __restrict__ Ko, short* __restrict__ V2S,
    int* __restrict__ counter) {
  __shared__ float swq[256], swk[256], swv[256], swo[256];
  __shared__ float sbq[16], sbk[16], sbv[16];
  __shared__ float red[4];
  int tid = threadIdx.x;
  if (blockIdx.x == 0 && tid == 0) *counter = 0;
  if (blockIdx.x < 1536) {
    int bid2 = blockIdx.x;
    int u    = bid2 & 7;        // 8-way split of the 16384-px quadrant
    int base = bid2 >> 3;       // original (m,ch,a,b) id, 0..191
    int b  = base & 1;
    int a  = (base >> 1) & 1;
    int ch = (base >> 2) & 15;
    int m  = base >> 6;
    float w00 = cw[ch*4+0], w01 = cw[ch*4+1], w10 = cw[ch*4+2], w11 = cw[ch*4+3];
    float bias = cb[ch];
    const float* xm = x + (size_t)m * 255 * 255;
    float sum = 0.f;
    #pragma unroll
    for (int it = 0; it < 8; ++it) {
      int p = u*2048 + it*256 + tid;
      int i = a*128 + (p >> 7);
      int j = b*128 + (p & 127);
      float x00 = (i >= 1 && j >= 1)   ? xm[(i-1)*255 + (j-1)] : 0.f;
      float x01 = (i >= 1 && j <= 254) ? xm[(i-1)*255 + j]     : 0.f;
      float x10 = (i <= 254 && j >= 1) ? xm[i*255 + (j-1)]     : 0.f;
      float x11 = (i <= 254 && j <= 254) ? xm[i*255 + j]       : 0.f;
      float v = fmaf(x00,w00, fmaf(x01,w01, fmaf(x10,w10, fmaf(x11,w11, bias))));
      sum += fmaxf(v, 0.f);
    }
    for (int o = 32; o; o >>= 1) sum += __shfl_down(sum, o, 64);
    int wid = tid >> 6, lane = tid & 63;
    if (lane == 0) red[wid] = sum;
    __syncthreads();
    if (tid == 0) sfp[bid2] = red[0]+red[1]+red[2]+red[3];   // raw partial
  } else {
    swq[tid] = wq[tid]; swk[tid] = wk[tid]; swv[tid] = wv[tid]; swo[tid] = wo[tid];
    if (tid < 16) { sbq[tid] = bq[tid]; sbk[tid] = bk[tid]; sbv[tid] = bv[tid]; }
    __syncthreads();
    int row = (blockIdx.x - 1536) * 256 + tid;
    int idx = act[row];
    const float4* f4 = (const float4*)(feat + (size_t)idx * 16);
    float4 a0 = f4[0], a1 = f4[1], a2 = f4[2], a3 = f4[3];
    float af[16] = {a0.x,a0.y,a0.z,a0.w, a1.x,a1.y,a1.z,a1.w,
                    a2.x,a2.y,a2.z,a2.w, a3.x,a3.y,a3.z,a3.w};
    float q[16], k[16], v[16];
    #pragma unroll
    for (int kk = 0; kk < 16; ++kk) {
      float aq = sbq[kk], ak = sbk[kk], av = sbv[kk];
      #pragma unroll
      for (int f = 0; f < 16; ++f) {
        aq = fmaf(af[f], swq[f*16+kk], aq);
        ak = fmaf(af[f], swk[f*16+kk], ak);
        av = fmaf(af[f], swv[f*16+kk], av);
      }
      q[kk] = aq; k[kk] = ak; v[kk] = av;
    }
    const float qs = 0.25f * LOG2E;
    int s  = row >> 5;
    int jj = row & 31;
    int hi = jj >> 4;
    int m2 = jj & 15;
    int gsw = m2 >> 2;
    int rsw = m2 & 3;
    size_t vbase = (size_t)s * 512 + (size_t)gsw * 128 + hi * 4 + rsw;
    #pragma unroll
    for (int kk = 0; kk < 16; ++kk) {
      float a = 0.f;
      #pragma unroll
      for (int f = 0; f < 16; ++f) a = fmaf(v[f], swo[f*16+kk], a);
      V2S[vbase + (size_t)kk * 8] = f2bf(a);
      Qo[(size_t)row*16 + kk] = f2bf(q[kk] * qs);
      Ko[(size_t)row*16 + kk] = f2bf(k[kk]);
    }
  }
}

// ---------------- K2: attn + MLP + scores + (last block) final softmax ------------
// R10-verbatim structure; cvec lanes now also do the deterministic 8-way conv
// partial reduce; packbf replaced by cvtpk2 (v_cvt_pk_bf16_f32, bit-identical).
__global__ __launch_bounds__(1024) void attn_score(
    const short* __restrict__ Qb, const short* __restrict__ Kb,
    const short* __restrict__ V2S, const float* __restrict__ sfp,
    const float* __restrict__ w1, const float* __restrict__ b1,
    const float* __restrict__ bo, const float* __restrict__ w2,
    float* __restrict__ scores, int* __restrict__ counter,
    float* __restrict__ outp) {
  __shared__ float sacc[16][32][16];
  __shared__ float sl[16][32];
  __shared__ float sw1[256];
  __shared__ float scv[16], sw2s[16];
  __shared__ float red2[16];
  __shared__ float sbc2[2];
  __shared__ int slastS;
  int tid = threadIdx.x;
  if (tid < 256) sw1[tid] = w1[192*16 + tid];
  if (tid < 16) {
    float c = b1[tid];
    for (int s = 0; s < 192; ++s) {
      const float* pp = sfp + s*8;
      float sv = ((pp[0]+pp[1])+(pp[2]+pp[3])) + ((pp[4]+pp[5])+(pp[6]+pp[7]));
      c = fmaf(sv * (1.0f/16384.0f), w1[s*16+tid], c);
    }
    for (int f = 0; f < 16; ++f)  c = fmaf(bo[f], w1[(192+f)*16+tid], c);
    scv[tid] = c;
    sw2s[tid] = w2[tid];
  }
  int w = tid >> 6, lane = tid & 63;
  int g = lane >> 4, fi = lane & 15;
  int i0 = blockIdx.x * 32;

  short8v z8 = {};
  short8v qfa = z8, qfb = z8;
  if (g < 2) {
    qfa = *(const short8v*)(Qb + (size_t)(i0 + fi)*16 + g*8);
    qfb = *(const short8v*)(Qb + (size_t)(i0 + 16 + fi)*16 + g*8);
  }
  const short* kp = Kb + (size_t)(w*512 + fi)*16 + g*8;
  const short* vp = V2S + (size_t)(w*1024 + lane)*8;

  f32x4 acca = {0.f,0.f,0.f,0.f}, accb = {0.f,0.f,0.f,0.f};
  float lsa = 0.f, lsb = 0.f;
  #pragma unroll 4
  for (int step = 0; step < 16; ++step) {
    short8v kf0 = z8, kf1 = z8;
    if (g < 2) {
      kf0 = *(const short8v*)(kp);
      kf1 = *(const short8v*)(kp + 256);   // +16 rows
    }
    i32x4 vv = *(const i32x4*)(vp);
    short8v vf = __builtin_bit_cast(short8v, vv);
    f32x4 zero4 = {0.f,0.f,0.f,0.f};
    f32x4 e0a = __builtin_amdgcn_mfma_f32_16x16x32_bf16(kf0, qfa, zero4, 0, 0, 0);
    f32x4 e1a = __builtin_amdgcn_mfma_f32_16x16x32_bf16(kf1, qfa, zero4, 0, 0, 0);
    f32x4 e0b = __builtin_amdgcn_mfma_f32_16x16x32_bf16(kf0, qfb, zero4, 0, 0, 0);
    f32x4 e1b = __builtin_amdgcn_mfma_f32_16x16x32_bf16(kf1, qfb, zero4, 0, 0, 0);
    {
      float p0 = fexp2(e0a[0]), p1 = fexp2(e0a[1]), p2 = fexp2(e0a[2]), p3 = fexp2(e0a[3]);
      float p4 = fexp2(e1a[0]), p5 = fexp2(e1a[1]), p6 = fexp2(e1a[2]), p7 = fexp2(e1a[3]);
      lsa += ((p0+p1)+(p2+p3)) + ((p4+p5)+(p6+p7));
      i32x4 pk;
      pk[0] = (int)cvtpk2(p0, p1); pk[1] = (int)cvtpk2(p2, p3);
      pk[2] = (int)cvtpk2(p4, p5); pk[3] = (int)cvtpk2(p6, p7);
      acca = __builtin_amdgcn_mfma_f32_16x16x32_bf16(__builtin_bit_cast(short8v, pk), vf, acca, 0, 0, 0);
    }
    {
      float p0 = fexp2(e0b[0]), p1 = fexp2(e0b[1]), p2 = fexp2(e0b[2]), p3 = fexp2(e0b[3]);
      float p4 = fexp2(e1b[0]), p5 = fexp2(e1b[1]), p6 = fexp2(e1b[2]), p7 = fexp2(e1b[3]);
      lsb += ((p0+p1)+(p2+p3)) + ((p4+p5)+(p6+p7));
      i32x4 pk;
      pk[0] = (int)cvtpk2(p0, p1); pk[1] = (int)cvtpk2(p2, p3);
      pk[2] = (int)cvtpk2(p4, p5); pk[3] = (int)cvtpk2(p6, p7);
      accb = __builtin_amdgcn_mfma_f32_16x16x32_bf16(__builtin_bit_cast(short8v, pk), vf, accb, 0, 0, 0);
    }
    kp += 512;  // 32 rows * 16
    vp += 512;  // 64 lanes * 8 shorts
  }
  lsa += __shfl_xor(lsa, 16, 64); lsa += __shfl_xor(lsa, 32, 64);
  lsb += __shfl_xor(lsb, 16, 64); lsb += __shfl_xor(lsb, 32, 64);
  #pragma unroll
  for (int r = 0; r < 4; ++r) {
    sacc[w][4*g + r][fi]      = acca[r];
    sacc[w][16 + 4*g + r][fi] = accb[r];
  }
  if (g == 0) { sl[w][fi] = lsa; sl[w][16 + fi] = lsb; }
  __syncthreads();
  if (tid < 512) {
    int i = tid >> 4, f = tid & 15;
    float o = 0.f, li = 0.f;
    #pragma unroll
    for (int wv = 0; wv < 16; ++wv) { o += sacc[wv][i][f]; li += sl[wv][i]; }
    sacc[0][i][f] = o / li;
  }
  __syncthreads();
  if (tid < 512) {
    int i = tid >> 4, k = tid & 15;
    float h = scv[k];
    #pragma unroll
    for (int f = 0; f < 16; ++f) h = fmaf(sacc[0][i][f], sw1[f*16+k], h);
    h = fmaxf(h, 0.f);
    float t = h * sw2s[k];
    t += __shfl_xor(t, 1, 64);
    t += __shfl_xor(t, 2, 64);
    t += __shfl_xor(t, 4, 64);
    t += __shfl_xor(t, 8, 64);
    if (k == 0)
      __hip_atomic_store(&scores[i0 + i], t, __ATOMIC_RELAXED, __HIP_MEMORY_SCOPE_AGENT);
  }
  __syncthreads();
  if (tid == 0)
    slastS = __hip_atomic_fetch_add(counter, 1, __ATOMIC_ACQ_REL, __HIP_MEMORY_SCOPE_AGENT);
  __syncthreads();
  if (slastS != (A_N/32) - 1) return;

  // ---- last block: final softmax over 8192 scores (register-cached) ----
  float sv[8];
  #pragma unroll
  for (int u = 0; u < 8; ++u)
    sv[u] = __hip_atomic_load(&scores[tid + u*1024], __ATOMIC_RELAXED, __HIP_MEMORY_SCOPE_AGENT);
  int lane2 = tid & 63, wid2 = tid >> 6;
  float m = -3.4e38f;
  #pragma unroll
  for (int u = 0; u < 8; ++u) m = fmaxf(m, sv[u]);
  for (int o = 32; o; o >>= 1) m = fmaxf(m, __shfl_down(m, o, 64));
  if (lane2 == 0) red2[wid2] = m;
  __syncthreads();
  if (tid == 0) {
    float mm = red2[0];
    for (int wv = 1; wv < 16; ++wv) mm = fmaxf(mm, red2[wv]);
    sbc2[0] = mm;
  }
  __syncthreads();
  float mx = sbc2[0];
  float s = 0.f;
  #pragma unroll
  for (int u = 0; u < 8; ++u) s += __expf(sv[u] - mx);
  for (int o = 32; o; o >>= 1) s += __shfl_down(s, o, 64);
  if (lane2 == 0) red2[wid2] = s;
  __syncthreads();
  if (tid == 0) {
    float ss = 0.f;
    for (int wv = 0; wv < 16; ++wv) ss += red2[wv];
    sbc2[1] = ss;
  }
  __syncthreads();
  float inv = 1.0f / sbc2[1];
  #pragma unroll
  for (int u = 0; u < 8; ++u)
    outp[tid + u*1024] = __expf(sv[u] - mx) * inv;
}

extern "C" void kernel_launch(void* const* d_in, const int* in_sizes, int n_in,
                              void* d_out, int out_size, void* d_ws, size_t ws_size,
                              hipStream_t stream) {
  const float* x      = (const float*)d_in[0];
  const int*   act    = (const int*)  d_in[1];
  const float* feat   = (const float*)d_in[2];
  const float* conv_w = (const float*)d_in[3];
  const float* conv_b = (const float*)d_in[4];
  const float* wq     = (const float*)d_in[5];
  const float* bq     = (const float*)d_in[6];
  const float* wk     = (const float*)d_in[7];
  const float* bk     = (const float*)d_in[8];
  const float* wv     = (const float*)d_in[9];
  const float* bv     = (const float*)d_in[10];
  const float* wo     = (const float*)d_in[11];
  const float* bo     = (const float*)d_in[12];
  const float* w1     = (const float*)d_in[13];
  const float* b1     = (const float*)d_in[14];
  const float* w2     = (const float*)d_in[15];
  // d_in[16] = mlp_b2: softmax shift-invariant, dropped.

  char* wsb = (char*)d_ws;
  float* sfp    = (float*)(wsb);             // 1536 conv partials
  int*   ctr    = (int*)  (wsb + 8192);      // completion counter
  float* scores = (float*)(wsb + 16384);     // 8192 floats
  short* Qb     = (short*)(wsb + 65536);             // 8192*16 bf16
  short* Kb     = (short*)(wsb + 65536 + 262144);    // 8192*16 bf16
  short* V2S    = (short*)(wsb + 65536 + 524288);    // 8192*16 bf16 (swizzled)
  float* out    = (float*)d_out;

  fused_pre  <<<1568, 256, 0, stream>>>(x, conv_w, conv_b, sfp,
                                        act, feat, wq, bq, wk, bk, wv, bv, wo,
                                        Qb, Kb, V2S, ctr);
  attn_score <<<A_N/32, 1024, 0, stream>>>(Qb, Kb, V2S, sfp, w1, b1, bo, w2,
                                           scores, ctr, out);
}

// Round 12
// 36.524 us; speedup vs baseline: 1.9892x; 1.1389x over previous
//
#include <hip/hip_runtime.h>
#include <hip/hip_bf16.h>

#define A_N 8192
#define LOG2E 1.44269504f

typedef __attribute__((ext_vector_type(8))) short short8v;
typedef __attribute__((ext_vector_type(4))) float f32x4;
typedef __attribute__((ext_vector_type(4))) int   i32x4;

__device__ inline short f2bf(float x) {
  unsigned u = __builtin_bit_cast(unsigned, x);
  unsigned r = (u + 0x7FFFu + ((u >> 16) & 1u)) >> 16;
  return (short)r;
}
// Compiler-visible exp2 (hazard-handled) — proven safe in R7.
__device__ inline float fexp2(float x) {
#if __has_builtin(__builtin_amdgcn_exp2f)
  return __builtin_amdgcn_exp2f(x);
#else
  return exp2f(x);
#endif
}
// Packed bf16 convert (RNE) via HIP intrinsic -> v_cvt_pk_bf16_f32, compiler-
// scheduled (hazard-safe). NOTE: never raw inline-asm feeding MFMA (R3-R5 bug).
__device__ inline unsigned cvtpk2(float lo, float hi) {
  float2 t; t.x = lo; t.y = hi;
  __hip_bfloat162 h = __float22bfloat162_rn(t);
  unsigned r; __builtin_memcpy(&r, &h, 4);
  return r;
}

// ---------------- K1: fused conv partials (blocks 0..1535) + qkv (1536..1567) -----
// R11-verbatim.
__global__ __launch_bounds__(256) void fused_pre(
    const float* __restrict__ x, const float* __restrict__ cw,
    const float* __restrict__ cb, float* __restrict__ sfp,
    const int* __restrict__ act, const float* __restrict__ feat,
    const float* __restrict__ wq, const float* __restrict__ bq,
    const float* __restrict__ wk, const float* __restrict__ bk,
    const float* __restrict__ wv, const float* __restrict__ bv,
    const float* __restrict__ wo,
    short* __restrict__ Qo, short* __restrict__ Ko, short* __restrict__ V2S,
    int* __restrict__ counter) {
  __shared__ float swq[256], swk[256], swv[256], swo[256];
  __shared__ float sbq[16], sbk[16], sbv[16];
  __shared__ float red[4];
  int tid = threadIdx.x;
  if (blockIdx.x == 0 && tid == 0) *counter = 0;
  if (blockIdx.x < 1536) {
    int bid2 = blockIdx.x;
    int u    = bid2 & 7;
    int base = bid2 >> 3;
    int b  = base & 1;
    int a  = (base >> 1) & 1;
    int ch = (base >> 2) & 15;
    int m  = base >> 6;
    float w00 = cw[ch*4+0], w01 = cw[ch*4+1], w10 = cw[ch*4+2], w11 = cw[ch*4+3];
    float bias = cb[ch];
    const float* xm = x + (size_t)m * 255 * 255;
    float sum = 0.f;
    #pragma unroll
    for (int it = 0; it < 8; ++it) {
      int p = u*2048 + it*256 + tid;
      int i = a*128 + (p >> 7);
      int j = b*128 + (p & 127);
      float x00 = (i >= 1 && j >= 1)   ? xm[(i-1)*255 + (j-1)] : 0.f;
      float x01 = (i >= 1 && j <= 254) ? xm[(i-1)*255 + j]     : 0.f;
      float x10 = (i <= 254 && j >= 1) ? xm[i*255 + (j-1)]     : 0.f;
      float x11 = (i <= 254 && j <= 254) ? xm[i*255 + j]       : 0.f;
      float v = fmaf(x00,w00, fmaf(x01,w01, fmaf(x10,w10, fmaf(x11,w11, bias))));
      sum += fmaxf(v, 0.f);
    }
    for (int o = 32; o; o >>= 1) sum += __shfl_down(sum, o, 64);
    int wid = tid >> 6, lane = tid & 63;
    if (lane == 0) red[wid] = sum;
    __syncthreads();
    if (tid == 0) sfp[bid2] = red[0]+red[1]+red[2]+red[3];
  } else {
    swq[tid] = wq[tid]; swk[tid] = wk[tid]; swv[tid] = wv[tid]; swo[tid] = wo[tid];
    if (tid < 16) { sbq[tid] = bq[tid]; sbk[tid] = bk[tid]; sbv[tid] = bv[tid]; }
    __syncthreads();
    int row = (blockIdx.x - 1536) * 256 + tid;
    int idx = act[row];
    const float4* f4 = (const float4*)(feat + (size_t)idx * 16);
    float4 a0 = f4[0], a1 = f4[1], a2 = f4[2], a3 = f4[3];
    float af[16] = {a0.x,a0.y,a0.z,a0.w, a1.x,a1.y,a1.z,a1.w,
                    a2.x,a2.y,a2.z,a2.w, a3.x,a3.y,a3.z,a3.w};
    float q[16], k[16], v[16];
    #pragma unroll
    for (int kk = 0; kk < 16; ++kk) {
      float aq = sbq[kk], ak = sbk[kk], av = sbv[kk];
      #pragma unroll
      for (int f = 0; f < 16; ++f) {
        aq = fmaf(af[f], swq[f*16+kk], aq);
        ak = fmaf(af[f], swk[f*16+kk], ak);
        av = fmaf(af[f], swv[f*16+kk], av);
      }
      q[kk] = aq; k[kk] = ak; v[kk] = av;
    }
    const float qs = 0.25f * LOG2E;
    int s  = row >> 5;
    int jj = row & 31;
    int hi = jj >> 4;
    int m2 = jj & 15;
    int gsw = m2 >> 2;
    int rsw = m2 & 3;
    size_t vbase = (size_t)s * 512 + (size_t)gsw * 128 + hi * 4 + rsw;
    #pragma unroll
    for (int kk = 0; kk < 16; ++kk) {
      float a = 0.f;
      #pragma unroll
      for (int f = 0; f < 16; ++f) a = fmaf(v[f], swo[f*16+kk], a);
      V2S[vbase + (size_t)kk * 8] = f2bf(a);
      Qo[(size_t)row*16 + kk] = f2bf(q[kk] * qs);
      Ko[(size_t)row*16 + kk] = f2bf(k[kk]);
    }
  }
}

// ---------------- K2: attn + MLP + scores + (last block) final softmax ------------
// R11 structure + (a) register prefetch double-buffer in main loop (builtins only),
// (b) parallel cvec partials (tid<256, 12 s-values each; reduced by tid 512..527
// between the epilogue barriers).
__global__ __launch_bounds__(1024) void attn_score(
    const short* __restrict__ Qb, const short* __restrict__ Kb,
    const short* __restrict__ V2S, const float* __restrict__ sfp,
    const float* __restrict__ w1, const float* __restrict__ b1,
    const float* __restrict__ bo, const float* __restrict__ w2,
    float* __restrict__ scores, int* __restrict__ counter,
    float* __restrict__ outp) {
  __shared__ float sacc[16][32][16];
  __shared__ float sl[16][32];
  __shared__ float sw1[256];
  __shared__ float scvp[16][16];
  __shared__ float scv[16], sw2s[16];
  __shared__ float red2[16];
  __shared__ float sbc2[2];
  __shared__ int slastS;
  int tid = threadIdx.x;
  if (tid < 256) {
    sw1[tid] = w1[192*16 + tid];
    int c4 = tid >> 4, kq = tid & 15;
    float acc = (c4 == 0) ? b1[kq] : 0.f;
    #pragma unroll
    for (int si = 0; si < 12; ++si) {
      int s = c4*12 + si;
      const float* pp = sfp + s*8;
      float sv = ((pp[0]+pp[1])+(pp[2]+pp[3])) + ((pp[4]+pp[5])+(pp[6]+pp[7]));
      acc = fmaf(sv * (1.0f/16384.0f), w1[s*16+kq], acc);
    }
    if (c4 == 1) {
      #pragma unroll
      for (int f = 0; f < 16; ++f) acc = fmaf(bo[f], w1[(192+f)*16+kq], acc);
    }
    scvp[c4][kq] = acc;
  }
  if (tid < 16) sw2s[tid] = w2[tid];
  int w = tid >> 6, lane = tid & 63;
  int g = lane >> 4, fi = lane & 15;
  int i0 = blockIdx.x * 32;

  short8v z8 = {};
  short8v qfa = z8, qfb = z8;
  if (g < 2) {
    qfa = *(const short8v*)(Qb + (size_t)(i0 + fi)*16 + g*8);
    qfb = *(const short8v*)(Qb + (size_t)(i0 + 16 + fi)*16 + g*8);
  }
  const short* kp = Kb + (size_t)(w*512 + fi)*16 + g*8;
  const short* vp = V2S + (size_t)(w*1024 + lane)*8;

  f32x4 acca = {0.f,0.f,0.f,0.f}, accb = {0.f,0.f,0.f,0.f};
  float lsa = 0.f, lsb = 0.f;

  short8v k0c = z8, k1c = z8; i32x4 vvc = {0,0,0,0};
  if (g < 2) { k0c = *(const short8v*)kp; k1c = *(const short8v*)(kp + 256); }
  vvc = *(const i32x4*)(vp);

  #pragma unroll 2
  for (int step = 0; step < 16; ++step) {
    short8v k0n = z8, k1n = z8; i32x4 vvn = {0,0,0,0};
    if (step < 15) {
      if (g < 2) {
        k0n = *(const short8v*)(kp + 512);
        k1n = *(const short8v*)(kp + 768);
      }
      vvn = *(const i32x4*)(vp + 512);
    }
    short8v vf = __builtin_bit_cast(short8v, vvc);
    f32x4 zero4 = {0.f,0.f,0.f,0.f};
    f32x4 e0a = __builtin_amdgcn_mfma_f32_16x16x32_bf16(k0c, qfa, zero4, 0, 0, 0);
    f32x4 e1a = __builtin_amdgcn_mfma_f32_16x16x32_bf16(k1c, qfa, zero4, 0, 0, 0);
    f32x4 e0b = __builtin_amdgcn_mfma_f32_16x16x32_bf16(k0c, qfb, zero4, 0, 0, 0);
    f32x4 e1b = __builtin_amdgcn_mfma_f32_16x16x32_bf16(k1c, qfb, zero4, 0, 0, 0);
    {
      float p0 = fexp2(e0a[0]), p1 = fexp2(e0a[1]), p2 = fexp2(e0a[2]), p3 = fexp2(e0a[3]);
      float p4 = fexp2(e1a[0]), p5 = fexp2(e1a[1]), p6 = fexp2(e1a[2]), p7 = fexp2(e1a[3]);
      lsa += ((p0+p1)+(p2+p3)) + ((p4+p5)+(p6+p7));
      i32x4 pk;
      pk[0] = (int)cvtpk2(p0, p1); pk[1] = (int)cvtpk2(p2, p3);
      pk[2] = (int)cvtpk2(p4, p5); pk[3] = (int)cvtpk2(p6, p7);
      acca = __builtin_amdgcn_mfma_f32_16x16x32_bf16(__builtin_bit_cast(short8v, pk), vf, acca, 0, 0, 0);
    }
    {
      float p0 = fexp2(e0b[0]), p1 = fexp2(e0b[1]), p2 = fexp2(e0b[2]), p3 = fexp2(e0b[3]);
      float p4 = fexp2(e1b[0]), p5 = fexp2(e1b[1]), p6 = fexp2(e1b[2]), p7 = fexp2(e1b[3]);
      lsb += ((p0+p1)+(p2+p3)) + ((p4+p5)+(p6+p7));
      i32x4 pk;
      pk[0] = (int)cvtpk2(p0, p1); pk[1] = (int)cvtpk2(p2, p3);
      pk[2] = (int)cvtpk2(p4, p5); pk[3] = (int)cvtpk2(p6, p7);
      accb = __builtin_amdgcn_mfma_f32_16x16x32_bf16(__builtin_bit_cast(short8v, pk), vf, accb, 0, 0, 0);
    }
    k0c = k0n; k1c = k1n; vvc = vvn;
    kp += 512;
    vp += 512;
  }
  lsa += __shfl_xor(lsa, 16, 64); lsa += __shfl_xor(lsa, 32, 64);
  lsb += __shfl_xor(lsb, 16, 64); lsb += __shfl_xor(lsb, 32, 64);
  #pragma unroll
  for (int r = 0; r < 4; ++r) {
    sacc[w][4*g + r][fi]      = acca[r];
    sacc[w][16 + 4*g + r][fi] = accb[r];
  }
  if (g == 0) { sl[w][fi] = lsa; sl[w][16 + fi] = lsb; }
  __syncthreads();
  if (tid < 512) {
    int i = tid >> 4, f = tid & 15;
    float o = 0.f, li = 0.f;
    #pragma unroll
    for (int wv = 0; wv < 16; ++wv) { o += sacc[wv][i][f]; li += sl[wv][i]; }
    sacc[0][i][f] = o / li;
  } else if (tid < 528) {
    int k = tid - 512;
    float s = 0.f;
    #pragma unroll
    for (int c = 0; c < 16; ++c) s += scvp[c][k];
    scv[k] = s;
  }
  __syncthreads();
  if (tid < 512) {
    int i = tid >> 4, k = tid & 15;
    float h = scv[k];
    #pragma unroll
    for (int f = 0; f < 16; ++f) h = fmaf(sacc[0][i][f], sw1[f*16+k], h);
    h = fmaxf(h, 0.f);
    float t = h * sw2s[k];
    t += __shfl_xor(t, 1, 64);
    t += __shfl_xor(t, 2, 64);
    t += __shfl_xor(t, 4, 64);
    t += __shfl_xor(t, 8, 64);
    if (k == 0)
      __hip_atomic_store(&scores[i0 + i], t, __ATOMIC_RELAXED, __HIP_MEMORY_SCOPE_AGENT);
  }
  __syncthreads();
  if (tid == 0)
    slastS = __hip_atomic_fetch_add(counter, 1, __ATOMIC_ACQ_REL, __HIP_MEMORY_SCOPE_AGENT);
  __syncthreads();
  if (slastS != (A_N/32) - 1) return;

  float sv[8];
  #pragma unroll
  for (int u = 0; u < 8; ++u)
    sv[u] = __hip_atomic_load(&scores[tid + u*1024], __ATOMIC_RELAXED, __HIP_MEMORY_SCOPE_AGENT);
  int lane2 = tid & 63, wid2 = tid >> 6;
  float m = -3.4e38f;
  #pragma unroll
  for (int u = 0; u < 8; ++u) m = fmaxf(m, sv[u]);
  for (int o = 32; o; o >>= 1) m = fmaxf(m, __shfl_down(m, o, 64));
  if (lane2 == 0) red2[wid2] = m;
  __syncthreads();
  if (tid == 0) {
    float mm = red2[0];
    for (int wv = 1; wv < 16; ++wv) mm = fmaxf(mm, red2[wv]);
    sbc2[0] = mm;
  }
  __syncthreads();
  float mx = sbc2[0];
  float s = 0.f;
  #pragma unroll
  for (int u = 0; u < 8; ++u) s += __expf(sv[u] - mx);
  for (int o = 32; o; o >>= 1) s += __shfl_down(s, o, 64);
  if (lane2 == 0) red2[wid2] = s;
  __syncthreads();
  if (tid == 0) {
    float ss = 0.f;
    for (int wv = 0; wv < 16; ++wv) ss += red2[wv];
    sbc2[1] = ss;
  }
  __syncthreads();
  float inv = 1.0f / sbc2[1];
  #pragma unroll
  for (int u = 0; u < 8; ++u)
    outp[tid + u*1024] = __expf(sv[u] - mx) * inv;
}

extern "C" void kernel_launch(void* const* d_in, const int* in_sizes, int n_in,
                              void* d_out, int out_size, void* d_ws, size_t ws_size,
                              hipStream_t stream) {
  const float* x      = (const float*)d_in[0];
  const int*   act    = (const int*)  d_in[1];
  const float* feat   = (const float*)d_in[2];
  const float* conv_w = (const float*)d_in[3];
  const float* conv_b = (const float*)d_in[4];
  const float* wq     = (const float*)d_in[5];
  const float* bq     = (const float*)d_in[6];
  const float* wk     = (const float*)d_in[7];
  const float* bk     = (const float*)d_in[8];
  const float* wv     = (const float*)d_in[9];
  const float* bv     = (const float*)d_in[10];
  const float* wo     = (const float*)d_in[11];
  const float* bo     = (const float*)d_in[12];
  const float* w1     = (const float*)d_in[13];
  const float* b1     = (const float*)d_in[14];
  const float* w2     = (const float*)d_in[15];
  // d_in[16] = mlp_b2: softmax shift-invariant, dropped.

  char* wsb = (char*)d_ws;
  float* sfp    = (float*)(wsb);             // 1536 conv partials
  int*   ctr    = (int*)  (wsb + 8192);      // completion counter
  float* scores = (float*)(wsb + 16384);     // 8192 floats
  short* Qb     = (short*)(wsb + 65536);             // 8192*16 bf16
  short* Kb     = (short*)(wsb + 65536 + 262144);    // 8192*16 bf16
  short* V2S    = (short*)(wsb + 65536 + 524288);    // 8192*16 bf16 (swizzled)
  float* out    = (float*)d_out;

  fused_pre  <<<1568, 256, 0, stream>>>(x, conv_w, conv_b, sfp,
                                        act, feat, wq, bq, wk, bk, wv, bv, wo,
                                        Qb, Kb, V2S, ctr);
  attn_score <<<A_N/32, 1024, 0, stream>>>(Qb, Kb, V2S, sfp, w1, b1, bo, w2,
                                           scores, ctr, out);
}